// Round 4
// baseline (263.128 us; speedup 1.0000x reference)
//
#include <hip/hip_runtime.h>
#include <hip/hip_bf16.h>

// ---------------- problem constants (fixed by setup_inputs) ----------------
#define NUM_B   16
#define DIM     512
#define TT      1500
#define NROWS   (NUM_B * TT)              // 24000
#define NCODES  4096
#define ROW_TILES ((NROWS + 127) / 128)   // 188
#define NROWS_PAD (ROW_TILES * 128)       // 24064
#define NSLICE  32                        // partial cd slices (atomic decontention)
#define SHIFTC  30.0f                     // exp shift: exp(SHIFT-d), cancels in softmax

typedef __bf16 bf16x8 __attribute__((ext_vector_type(8)));
typedef float  floatx4 __attribute__((ext_vector_type(4)));
typedef unsigned short ushortx8 __attribute__((ext_vector_type(8)));

// async global->LDS, 16B per lane; dest = wave-uniform base + lane*16
__device__ __forceinline__ void glds16(const void* g, void* l) {
    __builtin_amdgcn_global_load_lds(
        (__attribute__((address_space(1))) void*)(void*)g,
        (__attribute__((address_space(3))) void*)l, 16, 0, 0);
}

// ---------------- prep: transpose (B,D,T) fp32 -> (N,D) bf16 ----------------
__global__ void k_transpose(const float* __restrict__ sf, unsigned short* __restrict__ zbf) {
    __shared__ float tile[32][33];
    int tid = threadIdx.x;
    int b = blockIdx.z, d0 = blockIdx.y * 32, t0 = blockIdx.x * 32;
    int tl = tid & 31, dg = tid >> 5;
#pragma unroll
    for (int p = 0; p < 4; ++p) {
        int dl = p * 8 + dg;
        int t = t0 + tl;
        if (t < TT) tile[tl][dl] = sf[(size_t)(b * DIM + d0 + dl) * TT + t];
    }
    __syncthreads();
    int dl = tid & 31, tg = tid >> 5;
#pragma unroll
    for (int p = 0; p < 4; ++p) {
        int tl2 = p * 8 + tg;
        int t = t0 + tl2;
        if (t < TT) {
            __hip_bfloat16 h = __float2bfloat16(tile[tl2][dl]);
            zbf[(size_t)(b * TT + t) * DIM + d0 + dl] = __builtin_bit_cast(unsigned short, h);
        }
    }
}

// ---------------- prep: z2 from bf16 z ----------------
__global__ void k_z2(const unsigned short* __restrict__ zbf, float* __restrict__ z2) {
    int row = blockIdx.x * 4 + (threadIdx.x >> 6);
    int lane = threadIdx.x & 63;
    uint4 v = *(const uint4*)(zbf + (size_t)row * DIM + lane * 8);
    unsigned int u[4] = {v.x, v.y, v.z, v.w};
    float s = 0.f;
#pragma unroll
    for (int i = 0; i < 4; ++i) {
        float lo = __builtin_bit_cast(float, u[i] << 16);
        float hi = __builtin_bit_cast(float, u[i] & 0xffff0000u);
        s += lo * lo + hi * hi;
    }
#pragma unroll
    for (int off = 32; off >= 1; off >>= 1) s += __shfl_down(s, off);
    if (lane == 0) z2[row] = s;
}

// ---------------- prep: codebook fp32 -> bf16, c2 ----------------
__global__ void k_cb(const float* __restrict__ cb, unsigned short* __restrict__ cbbf,
                     float* __restrict__ c2) {
    int k = blockIdx.x * 4 + (threadIdx.x >> 6);
    int lane = threadIdx.x & 63;
    const float4* src = (const float4*)(cb + (size_t)k * DIM + lane * 8);
    float4 a = src[0], b2 = src[1];
    float vals[8] = {a.x, a.y, a.z, a.w, b2.x, b2.y, b2.z, b2.w};
    float s = 0.f;
    unsigned int h[8];
#pragma unroll
    for (int i = 0; i < 8; ++i) {
        __hip_bfloat16 hb = __float2bfloat16(vals[i]);
        h[i] = __builtin_bit_cast(unsigned short, hb);
        float vb = __bfloat162float(hb);
        s += vb * vb;
    }
    uint4 o;
    o.x = h[0] | (h[1] << 16); o.y = h[2] | (h[3] << 16);
    o.z = h[4] | (h[5] << 16); o.w = h[6] | (h[7] << 16);
    *(uint4*)(cbbf + (size_t)k * DIM + lane * 8) = o;
#pragma unroll
    for (int off = 32; off >= 1; off >>= 1) s += __shfl_down(s, off);
    if (lane == 0) c2[k] = s;
}

// ---------------- pass 1: GEMM + exp; accumulate S, store E bf16 ----------------
// 128x128 tile, BK=64, global_load_lds(16B) with XOR-swizzled K-groups.
// __launch_bounds__(256,4): LDS 34KB -> 4 blocks/CU, VGPR 56 << 128 cap.
__global__ __launch_bounds__(256, 4) void k_gemm1(
    const unsigned short* __restrict__ zbf, const unsigned short* __restrict__ cbbf,
    const float* __restrict__ z2, const float* __restrict__ c2,
    const int* __restrict__ lengths, const int* __restrict__ stride_p,
    float* __restrict__ Sg, unsigned short* __restrict__ Eg) {
    __shared__ unsigned short As[128 * 64];
    __shared__ unsigned short Bs[128 * 64];
    __shared__ float z2s[128], c2s[128];
    __shared__ unsigned char vldp[128];
    __shared__ int s_any;
    int tid = threadIdx.x;
    int r0 = blockIdx.y * 128, c0 = blockIdx.x * 128;
    if (tid == 0) s_any = 0;
    __syncthreads();
    if (tid < 128) {
        int n = r0 + tid;
        int valid = 0;
        if (n < NROWS) {
            int b = n / TT, t = n - b * TT;
            int stride = stride_p[0];
            int nv = lengths[b] / stride;
            if (nv > TT) nv = TT;
            valid = (t < nv);
        }
        if (valid) atomicOr(&s_any, 1);
        vldp[tid] = (unsigned char)valid;
        z2s[tid] = z2[r0 + tid];
        c2s[tid] = c2[c0 + tid];
    }
    __syncthreads();
    if (!s_any) return;   // fully-masked row tile: contributes nothing

    int wave = tid >> 6, lane = tid & 63;
    int l15 = lane & 15, l4 = lane >> 4;
    int wr = (wave >> 1) * 64, wc = (wave & 1) * 64;

    int srow = lane >> 3;
    int scg = (lane & 7) ^ srow;
    const unsigned short* ag = zbf + (size_t)(r0 + wave * 32 + srow) * DIM + scg * 8;
    const unsigned short* bg = cbbf + (size_t)(c0 + wave * 32 + srow) * DIM + scg * 8;
    unsigned short* al = As + (wave * 32) * 64;
    unsigned short* bl = Bs + (wave * 32) * 64;

    floatx4 acc[4][4];
    const floatx4 zero = {0.f, 0.f, 0.f, 0.f};
#pragma unroll
    for (int i = 0; i < 4; ++i)
#pragma unroll
        for (int j = 0; j < 4; ++j) acc[i][j] = zero;

    int sw = l15 & 7;

    for (int kc = 0; kc < 8; ++kc) {
#pragma unroll
        for (int q = 0; q < 4; ++q) {
            glds16(ag + (size_t)q * 8 * DIM + kc * 64, al + q * 8 * 64);
            glds16(bg + (size_t)q * 8 * DIM + kc * 64, bl + q * 8 * 64);
        }
        __syncthreads();
#pragma unroll
        for (int ks = 0; ks < 64; ks += 32) {
            int g = (ks >> 3) + l4;
            int pcg = g ^ sw;
            bf16x8 av[4], bv[4];
#pragma unroll
            for (int i = 0; i < 4; ++i)
                av[i] = __builtin_bit_cast(bf16x8,
                    *(const ushortx8*)&As[(wr + 16 * i + l15) * 64 + pcg * 8]);
#pragma unroll
            for (int j = 0; j < 4; ++j)
                bv[j] = __builtin_bit_cast(bf16x8,
                    *(const ushortx8*)&Bs[(wc + 16 * j + l15) * 64 + pcg * 8]);
#pragma unroll
            for (int i = 0; i < 4; ++i)
#pragma unroll
                for (int j = 0; j < 4; ++j)
                    acc[i][j] = __builtin_amdgcn_mfma_f32_16x16x32_bf16(av[i], bv[j], acc[i][j], 0, 0, 0);
        }
        __syncthreads();
    }

    // epilogue: e = exp(SHIFT - sqrt(z2+c2-2*dot)); S += row-sum; E[n][k] = bf16(e)
    // C/D layout (m89-verified): col = lane&15, row = (lane>>4)*4 + reg
    // rv is uniform within each 16-lane group (rl depends only on l4) -> shuffles safe
#pragma unroll
    for (int i = 0; i < 4; ++i) {
#pragma unroll
        for (int r = 0; r < 4; ++r) {
            int rl = wr + 16 * i + 4 * l4 + r;
            if (!vldp[rl]) continue;
            float z2v = z2s[rl];
            float s = 0.f;
            unsigned short* Ep = Eg + (size_t)(r0 + rl) * NCODES + c0 + wc + l15;
#pragma unroll
            for (int j = 0; j < 4; ++j) {
                int cl = wc + 16 * j + l15;
                float d2 = z2v + c2s[cl] - 2.0f * acc[i][j][r];
                float d = sqrtf(fmaxf(d2, 1e-12f));
                float e = __expf(SHIFTC - d);
                s += e;
                Ep[16 * j] = __builtin_bit_cast(unsigned short, __float2bfloat16(e));
            }
            s += __shfl_xor(s, 1); s += __shfl_xor(s, 2);
            s += __shfl_xor(s, 4); s += __shfl_xor(s, 8);
            if (l15 == 0) atomicAdd(&Sg[r0 + rl], s);
        }
    }
}

// ---------------- pass 2: memory-bound scan  cdp[slice][k] += E[n][k]/S[n] ------
// block: 32 rows x 2048 cols (256 threads x 8 cols). grid (2, 752) = 1504 blocks.
__global__ __launch_bounds__(256) void k_scan(
    const unsigned short* __restrict__ Eg, const float* __restrict__ Sg,
    const int* __restrict__ lengths, const int* __restrict__ stride_p,
    float* __restrict__ cdp) {
    __shared__ float rs[32];
    __shared__ int s_any;
    int tid = threadIdx.x;
    int r0 = blockIdx.y * 32;
    if (tid == 0) s_any = 0;
    __syncthreads();
    if (tid < 32) {
        int n = r0 + tid;
        int valid = 0;
        if (n < NROWS) {
            int b = n / TT, t = n - b * TT;
            int nv = lengths[b] / stride_p[0];
            if (nv > TT) nv = TT;
            valid = (t < nv);
        }
        if (valid) atomicOr(&s_any, 1);
        rs[tid] = valid ? 1.0f / Sg[n] : 0.0f;
    }
    __syncthreads();
    if (!s_any) return;

    int col0 = blockIdx.x * 2048 + tid * 8;
    float acc[8] = {0.f, 0.f, 0.f, 0.f, 0.f, 0.f, 0.f, 0.f};
    for (int nn = 0; nn < 32; ++nn) {
        float rn = rs[nn];
        if (rn == 0.f) continue;        // wave-uniform: prefix-mask rows skip
        uint4 v = *(const uint4*)(Eg + (size_t)(r0 + nn) * NCODES + col0);
        unsigned int u[4] = {v.x, v.y, v.z, v.w};
#pragma unroll
        for (int q = 0; q < 4; ++q) {
            acc[2 * q]     += rn * __builtin_bit_cast(float, u[q] << 16);
            acc[2 * q + 1] += rn * __builtin_bit_cast(float, u[q] & 0xffff0000u);
        }
    }
    float* outp = cdp + (size_t)(blockIdx.y & (NSLICE - 1)) * NCODES;
#pragma unroll
    for (int t = 0; t < 8; ++t) atomicAdd(&outp[col0 + t], acc[t]);
}

// ---------------- fallback (small ws): two-pass GEMM (writes cdp slice 0) -------
template <int PASS>
__global__ __launch_bounds__(256, 4) void k_gemm(
    const unsigned short* __restrict__ zbf, const unsigned short* __restrict__ cbbf,
    const float* __restrict__ z2, const float* __restrict__ c2,
    const int* __restrict__ lengths, const int* __restrict__ stride_p,
    float* __restrict__ Sg, float* __restrict__ cd) {
    __shared__ unsigned short As[128 * 64];
    __shared__ unsigned short Bs[128 * 64];
    __shared__ float z2s[128], c2s[128], rs[128];
    __shared__ int s_any;
    int tid = threadIdx.x;
    int r0 = blockIdx.y * 128, c0 = blockIdx.x * 128;
    if (tid == 0) s_any = 0;
    __syncthreads();
    if (tid < 128) {
        int n = r0 + tid;
        int valid = 0;
        if (n < NROWS) {
            int b = n / TT, t = n - b * TT;
            int stride = stride_p[0];
            int nv = lengths[b] / stride;
            if (nv > TT) nv = TT;
            valid = (t < nv);
        }
        if (valid) atomicOr(&s_any, 1);
        z2s[tid] = z2[r0 + tid];
        c2s[tid] = c2[c0 + tid];
        if (PASS == 2) rs[tid] = valid ? (1.0f / Sg[r0 + tid]) : 0.0f;
    }
    __syncthreads();
    if (!s_any) return;

    int wave = tid >> 6, lane = tid & 63;
    int l15 = lane & 15, l4 = lane >> 4;
    int wr = (wave >> 1) * 64, wc = (wave & 1) * 64;
    int srow = lane >> 3;
    int scg = (lane & 7) ^ srow;
    const unsigned short* ag = zbf + (size_t)(r0 + wave * 32 + srow) * DIM + scg * 8;
    const unsigned short* bg = cbbf + (size_t)(c0 + wave * 32 + srow) * DIM + scg * 8;
    unsigned short* al = As + (wave * 32) * 64;
    unsigned short* bl = Bs + (wave * 32) * 64;

    floatx4 acc[4][4];
    const floatx4 zero = {0.f, 0.f, 0.f, 0.f};
#pragma unroll
    for (int i = 0; i < 4; ++i)
#pragma unroll
        for (int j = 0; j < 4; ++j) acc[i][j] = zero;
    int sw = l15 & 7;
    for (int kc = 0; kc < 8; ++kc) {
#pragma unroll
        for (int q = 0; q < 4; ++q) {
            glds16(ag + (size_t)q * 8 * DIM + kc * 64, al + q * 8 * 64);
            glds16(bg + (size_t)q * 8 * DIM + kc * 64, bl + q * 8 * 64);
        }
        __syncthreads();
#pragma unroll
        for (int ks = 0; ks < 64; ks += 32) {
            int g = (ks >> 3) + l4;
            int pcg = g ^ sw;
            bf16x8 av[4], bv[4];
#pragma unroll
            for (int i = 0; i < 4; ++i)
                av[i] = __builtin_bit_cast(bf16x8, *(const ushortx8*)&As[(wr + 16 * i + l15) * 64 + pcg * 8]);
#pragma unroll
            for (int j = 0; j < 4; ++j)
                bv[j] = __builtin_bit_cast(bf16x8, *(const ushortx8*)&Bs[(wc + 16 * j + l15) * 64 + pcg * 8]);
#pragma unroll
            for (int i = 0; i < 4; ++i)
#pragma unroll
                for (int j = 0; j < 4; ++j)
                    acc[i][j] = __builtin_amdgcn_mfma_f32_16x16x32_bf16(av[i], bv[j], acc[i][j], 0, 0, 0);
        }
        __syncthreads();
    }
    if (PASS == 1) {
#pragma unroll
        for (int i = 0; i < 4; ++i) {
#pragma unroll
            for (int r = 0; r < 4; ++r) {
                int rl = wr + 16 * i + 4 * l4 + r;
                float z2v = z2s[rl];
                float s = 0.f;
#pragma unroll
                for (int j = 0; j < 4; ++j) {
                    int cl = wc + 16 * j + l15;
                    float d2 = z2v + c2s[cl] - 2.0f * acc[i][j][r];
                    float d = sqrtf(fmaxf(d2, 1e-12f));
                    s += __expf(SHIFTC - d);
                }
                s += __shfl_xor(s, 1); s += __shfl_xor(s, 2);
                s += __shfl_xor(s, 4); s += __shfl_xor(s, 8);
                if (l15 == 0) atomicAdd(&Sg[r0 + rl], s);
            }
        }
    } else {
#pragma unroll
        for (int j = 0; j < 4; ++j) {
            int cl = wc + 16 * j + l15;
            float c2v = c2s[cl];
            float cs = 0.f;
#pragma unroll
            for (int i = 0; i < 4; ++i) {
#pragma unroll
                for (int r = 0; r < 4; ++r) {
                    int rl = wr + 16 * i + 4 * l4 + r;
                    float d2 = z2s[rl] + c2v - 2.0f * acc[i][j][r];
                    float d = sqrtf(fmaxf(d2, 1e-12f));
                    cs += __expf(SHIFTC - d) * rs[rl];
                }
            }
            cs += __shfl_xor(cs, 16); cs += __shfl_xor(cs, 32);
            if (l4 == 0) atomicAdd(&cd[c0 + cl], cs);
        }
    }
}

// ---------------- finalize: reduce slices, normalize, entropy ----------------
__global__ void k_final(float* __restrict__ cdp, float* __restrict__ out) {
    __shared__ float red[4];
    __shared__ float tot_s;
    int tid = threadIdx.x, lane = tid & 63, wave = tid >> 6;
    float t = 0.f;
    for (int i = tid; i < NCODES; i += 256) {
        float v = 0.f;
#pragma unroll
        for (int s = 0; s < NSLICE; ++s) v += cdp[(size_t)s * NCODES + i];
        cdp[i] = v;          // stash summed value in slice 0 (one thread per i)
        t += v;
    }
#pragma unroll
    for (int off = 32; off >= 1; off >>= 1) t += __shfl_down(t, off);
    if (lane == 0) red[wave] = t;
    __syncthreads();
    if (tid == 0) tot_s = red[0] + red[1] + red[2] + red[3];
    __syncthreads();
    float inv = 1.0f / (tot_s + 1e-8f);
    float e = 0.f;
    for (int i = tid; i < NCODES; i += 256) {
        float p = cdp[i] * inv;
        e += p * __logf(p + 1e-8f);
    }
#pragma unroll
    for (int off = 32; off >= 1; off >>= 1) e += __shfl_down(e, off);
    if (lane == 0) red[wave] = e;
    __syncthreads();
    if (tid == 0) {
        float ent = -(red[0] + red[1] + red[2] + red[3]);
        out[0] = 1.0f - ent / __logf((float)NCODES);
    }
}

// ---------------- launcher ----------------
extern "C" void kernel_launch(void* const* d_in, const int* in_sizes, int n_in,
                              void* d_out, int out_size, void* d_ws, size_t ws_size,
                              hipStream_t stream) {
    const float* sf = (const float*)d_in[0];
    const float* cb = (const float*)d_in[1];
    const int* lengths = (const int*)d_in[2];
    const int* stride_p = (const int*)d_in[3];

    float* Sg = (float*)d_ws;                      // NROWS_PAD
    float* cdp = Sg + NROWS_PAD;                   // NSLICE * NCODES
    float* z2 = cdp + (size_t)NSLICE * NCODES;     // NROWS_PAD
    float* c2 = z2 + NROWS_PAD;                    // NCODES
    unsigned short* zbf = (unsigned short*)(c2 + NCODES);       // NROWS_PAD*DIM bf16
    unsigned short* cbbf = zbf + (size_t)NROWS_PAD * DIM;       // NCODES*DIM bf16
    unsigned short* Eg = cbbf + (size_t)NCODES * DIM;           // NROWS_PAD*NCODES bf16

    size_t base_bytes = (size_t)(2 * NROWS_PAD + NCODES) * 4
                      + (size_t)NSLICE * NCODES * 4
                      + ((size_t)NROWS_PAD * DIM + (size_t)NCODES * DIM) * 2;
    size_t need = base_bytes + (size_t)NROWS_PAD * NCODES * 2;

    hipMemsetAsync(Sg, 0, ((size_t)NROWS_PAD + (size_t)NSLICE * NCODES) * sizeof(float), stream);
    k_transpose<<<dim3((TT + 31) / 32, DIM / 32, NUM_B), 256, 0, stream>>>(sf, zbf);
    k_cb<<<dim3(NCODES / 4), 256, 0, stream>>>(cb, cbbf, c2);
    k_z2<<<dim3(NROWS_PAD / 4), 256, 0, stream>>>(zbf, z2);
    if (ws_size >= need) {
        k_gemm1<<<dim3(NCODES / 128, ROW_TILES), 256, 0, stream>>>(zbf, cbbf, z2, c2, lengths, stride_p, Sg, Eg);
        k_scan<<<dim3(NCODES / 2048, NROWS_PAD / 32), 256, 0, stream>>>(Eg, Sg, lengths, stride_p, cdp);
    } else {
        k_gemm<1><<<dim3(NCODES / 128, ROW_TILES), 256, 0, stream>>>(zbf, cbbf, z2, c2, lengths, stride_p, Sg, cdp);
        k_gemm<2><<<dim3(NCODES / 128, ROW_TILES), 256, 0, stream>>>(zbf, cbbf, z2, c2, lengths, stride_p, Sg, cdp);
    }
    k_final<<<1, 256, 0, stream>>>(cdp, (float*)d_out);
}

// Round 5
// 236.156 us; speedup vs baseline: 1.1142x; 1.1142x over previous
//
#include <hip/hip_runtime.h>
#include <hip/hip_bf16.h>

// ---------------- problem constants (fixed by setup_inputs) ----------------
#define NUM_B   16
#define DIM     512
#define TT      1500
#define NROWS   (NUM_B * TT)              // 24000
#define NCODES  4096
#define ROW_TILES ((NROWS + 127) / 128)   // 188
#define NROWS_PAD (ROW_TILES * 128)       // 24064
#define NSLICE  8                         // partial cd slices (atomic decontention)
#define SHIFTC  30.0f                     // exp shift: exp(SHIFT-d), cancels in softmax

typedef __bf16 bf16x8 __attribute__((ext_vector_type(8)));
typedef float  floatx4 __attribute__((ext_vector_type(4)));
typedef unsigned short ushortx8 __attribute__((ext_vector_type(8)));

// async global->LDS, 16B per lane; dest = wave-uniform base + lane*16
__device__ __forceinline__ void glds16(const void* g, void* l) {
    __builtin_amdgcn_global_load_lds(
        (__attribute__((address_space(1))) void*)(void*)g,
        (__attribute__((address_space(3))) void*)l, 16, 0, 0);
}

// ---------------- prep: transpose (B,D,T) fp32 -> (N,D) bf16, fused z2 ------
__global__ void k_transpose(const float* __restrict__ sf, unsigned short* __restrict__ zbf,
                            float* __restrict__ z2) {
    __shared__ float tile[32][33];
    int tid = threadIdx.x;
    int b = blockIdx.z, d0 = blockIdx.y * 32, t0 = blockIdx.x * 32;
    int tl = tid & 31, dg = tid >> 5;
#pragma unroll
    for (int p = 0; p < 4; ++p) {
        int dl = p * 8 + dg;
        int t = t0 + tl;
        if (t < TT) tile[tl][dl] = sf[(size_t)(b * DIM + d0 + dl) * TT + t];
    }
    __syncthreads();
    int dl = tid & 31, tg = tid >> 5;
#pragma unroll
    for (int p = 0; p < 4; ++p) {
        int tl2 = p * 8 + tg;
        int t = t0 + tl2;
        float ssq = 0.f;
        if (t < TT) {
            __hip_bfloat16 h = __float2bfloat16(tile[tl2][dl]);
            zbf[(size_t)(b * TT + t) * DIM + d0 + dl] = __builtin_bit_cast(unsigned short, h);
            float vb = __bfloat162float(h);
            ssq = vb * vb;
        }
        // reduce across the 32 lanes sharing this row (dl = lane bits 0..4)
        ssq += __shfl_xor(ssq, 16); ssq += __shfl_xor(ssq, 8);
        ssq += __shfl_xor(ssq, 4);  ssq += __shfl_xor(ssq, 2);
        ssq += __shfl_xor(ssq, 1);
        if (dl == 0 && t < TT) atomicAdd(&z2[b * TT + t], ssq);
    }
}

// ---------------- prep: codebook fp32 -> bf16, c2 ----------------
__global__ void k_cb(const float* __restrict__ cb, unsigned short* __restrict__ cbbf,
                     float* __restrict__ c2) {
    int k = blockIdx.x * 4 + (threadIdx.x >> 6);
    int lane = threadIdx.x & 63;
    const float4* src = (const float4*)(cb + (size_t)k * DIM + lane * 8);
    float4 a = src[0], b2 = src[1];
    float vals[8] = {a.x, a.y, a.z, a.w, b2.x, b2.y, b2.z, b2.w};
    float s = 0.f;
    unsigned int h[8];
#pragma unroll
    for (int i = 0; i < 8; ++i) {
        __hip_bfloat16 hb = __float2bfloat16(vals[i]);
        h[i] = __builtin_bit_cast(unsigned short, hb);
        float vb = __bfloat162float(hb);
        s += vb * vb;
    }
    uint4 o;
    o.x = h[0] | (h[1] << 16); o.y = h[2] | (h[3] << 16);
    o.z = h[4] | (h[5] << 16); o.w = h[6] | (h[7] << 16);
    *(uint4*)(cbbf + (size_t)k * DIM + lane * 8) = o;
#pragma unroll
    for (int off = 32; off >= 1; off >>= 1) s += __shfl_down(s, off);
    if (lane == 0) c2[k] = s;
}

// ---------------- pass 1: GEMM + exp; accumulate S, store E (permuted bf16) ----
// 128x128 tile, BK=64, global_load_lds(16B) with XOR-swizzled K-groups.
// E layout: within each 64-col group, phys = l15*4 + j, logical col = 16*j + l15.
__global__ __launch_bounds__(256, 2) void k_gemm1(
    const unsigned short* __restrict__ zbf, const unsigned short* __restrict__ cbbf,
    const float* __restrict__ z2, const float* __restrict__ c2,
    const int* __restrict__ lengths, const int* __restrict__ stride_p,
    float* __restrict__ Sg, unsigned short* __restrict__ Eg) {
    __shared__ unsigned short As[128 * 64];
    __shared__ unsigned short Bs[128 * 64];
    __shared__ float z2s[128], c2s[128];
    __shared__ unsigned char vldp[128];
    __shared__ int s_any;
    int tid = threadIdx.x;
    int r0 = blockIdx.y * 128, c0 = blockIdx.x * 128;
    if (tid == 0) s_any = 0;
    __syncthreads();
    if (tid < 128) {
        int n = r0 + tid;
        int valid = 0;
        if (n < NROWS) {
            int b = n / TT, t = n - b * TT;
            int stride = stride_p[0];
            int nv = lengths[b] / stride;
            if (nv > TT) nv = TT;
            valid = (t < nv);
        }
        if (valid) atomicOr(&s_any, 1);
        vldp[tid] = (unsigned char)valid;
        z2s[tid] = z2[r0 + tid];
        c2s[tid] = c2[c0 + tid];
    }
    __syncthreads();
    if (!s_any) return;   // fully-masked row tile: contributes nothing

    int wave = tid >> 6, lane = tid & 63;
    int l15 = lane & 15, l4 = lane >> 4;
    int wr = (wave >> 1) * 64, wc = (wave & 1) * 64;

    int srow = lane >> 3;
    int scg = (lane & 7) ^ srow;
    const unsigned short* ag = zbf + (size_t)(r0 + wave * 32 + srow) * DIM + scg * 8;
    const unsigned short* bg = cbbf + (size_t)(c0 + wave * 32 + srow) * DIM + scg * 8;
    unsigned short* al = As + (wave * 32) * 64;
    unsigned short* bl = Bs + (wave * 32) * 64;

    floatx4 acc[4][4];
    const floatx4 zero = {0.f, 0.f, 0.f, 0.f};
#pragma unroll
    for (int i = 0; i < 4; ++i)
#pragma unroll
        for (int j = 0; j < 4; ++j) acc[i][j] = zero;

    int sw = l15 & 7;

    for (int kc = 0; kc < 8; ++kc) {
#pragma unroll
        for (int q = 0; q < 4; ++q) {
            glds16(ag + (size_t)q * 8 * DIM + kc * 64, al + q * 8 * 64);
            glds16(bg + (size_t)q * 8 * DIM + kc * 64, bl + q * 8 * 64);
        }
        __syncthreads();
#pragma unroll
        for (int ks = 0; ks < 64; ks += 32) {
            int g = (ks >> 3) + l4;
            int pcg = g ^ sw;
            bf16x8 av[4], bv[4];
#pragma unroll
            for (int i = 0; i < 4; ++i)
                av[i] = __builtin_bit_cast(bf16x8,
                    *(const ushortx8*)&As[(wr + 16 * i + l15) * 64 + pcg * 8]);
#pragma unroll
            for (int j = 0; j < 4; ++j)
                bv[j] = __builtin_bit_cast(bf16x8,
                    *(const ushortx8*)&Bs[(wc + 16 * j + l15) * 64 + pcg * 8]);
#pragma unroll
            for (int i = 0; i < 4; ++i)
#pragma unroll
                for (int j = 0; j < 4; ++j)
                    acc[i][j] = __builtin_amdgcn_mfma_f32_16x16x32_bf16(av[i], bv[j], acc[i][j], 0, 0, 0);
        }
        __syncthreads();
    }

    // epilogue: e = exp(SHIFT - sqrt(z2+c2-2*dot)); S += row-sum; E packed bf16 x4
    // C/D layout (m89-verified): col = lane&15, row = (lane>>4)*4 + reg
#pragma unroll
    for (int i = 0; i < 4; ++i) {
#pragma unroll
        for (int r = 0; r < 4; ++r) {
            int rl = wr + 16 * i + 4 * l4 + r;
            bool rv = vldp[rl] != 0;
            float z2v = z2s[rl];
            float s = 0.f;
            unsigned int hh[4];
#pragma unroll
            for (int j = 0; j < 4; ++j) {
                int cl = wc + 16 * j + l15;
                float d2 = fmaf(-2.0f, acc[i][j][r], z2v + c2s[cl]);
                float d = sqrtf(fmaxf(d2, 1e-12f));
                float e = __expf(SHIFTC - d);
                s += e;
                hh[j] = __builtin_bit_cast(unsigned short, __float2bfloat16(e));
            }
            if (rv) {
                uint2 pk;
                pk.x = hh[0] | (hh[1] << 16);
                pk.y = hh[2] | (hh[3] << 16);
                *(uint2*)(Eg + (size_t)(r0 + rl) * NCODES + c0 + wc + l15 * 4) = pk;
            }
            s += __shfl_xor(s, 1); s += __shfl_xor(s, 2);
            s += __shfl_xor(s, 4); s += __shfl_xor(s, 8);
            if (l15 == 0 && rv) atomicAdd(&Sg[r0 + rl], s);
        }
    }
}

// ---------------- pass 2: memory-bound scan  cdp[slice][k] += E[n][k]/S[n] ------
// block: 32 rows x 2048 physical cols (256 threads x 8). De-permutes E layout.
__global__ __launch_bounds__(256) void k_scan(
    const unsigned short* __restrict__ Eg, const float* __restrict__ Sg,
    const int* __restrict__ lengths, const int* __restrict__ stride_p,
    float* __restrict__ cdp) {
    __shared__ float rs[32];
    __shared__ int s_any;
    int tid = threadIdx.x;
    int r0 = blockIdx.y * 32;
    if (tid == 0) s_any = 0;
    __syncthreads();
    if (tid < 32) {
        int n = r0 + tid;
        int valid = 0;
        if (n < NROWS) {
            int b = n / TT, t = n - b * TT;
            int nv = lengths[b] / stride_p[0];
            if (nv > TT) nv = TT;
            valid = (t < nv);
        }
        if (valid) atomicOr(&s_any, 1);
        rs[tid] = valid ? 1.0f / Sg[n] : 0.0f;
    }
    __syncthreads();
    if (!s_any) return;

    int p0 = blockIdx.x * 2048 + tid * 8;     // physical offset in E row
    float acc[8] = {0.f, 0.f, 0.f, 0.f, 0.f, 0.f, 0.f, 0.f};
    for (int nn = 0; nn < 32; ++nn) {
        float rn = rs[nn];
        if (rn == 0.f) continue;        // wave-uniform: prefix-mask rows skip
        uint4 v = *(const uint4*)(Eg + (size_t)(r0 + nn) * NCODES + p0);
        unsigned int u[4] = {v.x, v.y, v.z, v.w};
#pragma unroll
        for (int q = 0; q < 4; ++q) {
            acc[2 * q]     += rn * __builtin_bit_cast(float, u[q] << 16);
            acc[2 * q + 1] += rn * __builtin_bit_cast(float, u[q] & 0xffff0000u);
        }
    }
    // de-permute: phys p in 64-group -> logical col = base + 16*(p&3) + (p>>2)
    int gbase = p0 & ~63;
    int l15a = (p0 & 63) >> 2;
    float* outp = cdp + (size_t)(blockIdx.y & (NSLICE - 1)) * NCODES;
#pragma unroll
    for (int t = 0; t < 8; ++t) {
        int col = gbase + 16 * (t & 3) + l15a + (t >> 2);
        atomicAdd(&outp[col], acc[t]);
    }
}

// ---------------- fallback (small ws): two-pass GEMM (writes cdp slice 0) -------
template <int PASS>
__global__ __launch_bounds__(256, 2) void k_gemm(
    const unsigned short* __restrict__ zbf, const unsigned short* __restrict__ cbbf,
    const float* __restrict__ z2, const float* __restrict__ c2,
    const int* __restrict__ lengths, const int* __restrict__ stride_p,
    float* __restrict__ Sg, float* __restrict__ cd) {
    __shared__ unsigned short As[128 * 64];
    __shared__ unsigned short Bs[128 * 64];
    __shared__ float z2s[128], c2s[128], rs[128];
    __shared__ int s_any;
    int tid = threadIdx.x;
    int r0 = blockIdx.y * 128, c0 = blockIdx.x * 128;
    if (tid == 0) s_any = 0;
    __syncthreads();
    if (tid < 128) {
        int n = r0 + tid;
        int valid = 0;
        if (n < NROWS) {
            int b = n / TT, t = n - b * TT;
            int stride = stride_p[0];
            int nv = lengths[b] / stride;
            if (nv > TT) nv = TT;
            valid = (t < nv);
        }
        if (valid) atomicOr(&s_any, 1);
        z2s[tid] = z2[r0 + tid];
        c2s[tid] = c2[c0 + tid];
        if (PASS == 2) rs[tid] = valid ? (1.0f / Sg[r0 + tid]) : 0.0f;
    }
    __syncthreads();
    if (!s_any) return;

    int wave = tid >> 6, lane = tid & 63;
    int l15 = lane & 15, l4 = lane >> 4;
    int wr = (wave >> 1) * 64, wc = (wave & 1) * 64;
    int srow = lane >> 3;
    int scg = (lane & 7) ^ srow;
    const unsigned short* ag = zbf + (size_t)(r0 + wave * 32 + srow) * DIM + scg * 8;
    const unsigned short* bg = cbbf + (size_t)(c0 + wave * 32 + srow) * DIM + scg * 8;
    unsigned short* al = As + (wave * 32) * 64;
    unsigned short* bl = Bs + (wave * 32) * 64;

    floatx4 acc[4][4];
    const floatx4 zero = {0.f, 0.f, 0.f, 0.f};
#pragma unroll
    for (int i = 0; i < 4; ++i)
#pragma unroll
        for (int j = 0; j < 4; ++j) acc[i][j] = zero;
    int sw = l15 & 7;
    for (int kc = 0; kc < 8; ++kc) {
#pragma unroll
        for (int q = 0; q < 4; ++q) {
            glds16(ag + (size_t)q * 8 * DIM + kc * 64, al + q * 8 * 64);
            glds16(bg + (size_t)q * 8 * DIM + kc * 64, bl + q * 8 * 64);
        }
        __syncthreads();
#pragma unroll
        for (int ks = 0; ks < 64; ks += 32) {
            int g = (ks >> 3) + l4;
            int pcg = g ^ sw;
            bf16x8 av[4], bv[4];
#pragma unroll
            for (int i = 0; i < 4; ++i)
                av[i] = __builtin_bit_cast(bf16x8, *(const ushortx8*)&As[(wr + 16 * i + l15) * 64 + pcg * 8]);
#pragma unroll
            for (int j = 0; j < 4; ++j)
                bv[j] = __builtin_bit_cast(bf16x8, *(const ushortx8*)&Bs[(wc + 16 * j + l15) * 64 + pcg * 8]);
#pragma unroll
            for (int i = 0; i < 4; ++i)
#pragma unroll
                for (int j = 0; j < 4; ++j)
                    acc[i][j] = __builtin_amdgcn_mfma_f32_16x16x32_bf16(av[i], bv[j], acc[i][j], 0, 0, 0);
        }
        __syncthreads();
    }
    if (PASS == 1) {
#pragma unroll
        for (int i = 0; i < 4; ++i) {
#pragma unroll
            for (int r = 0; r < 4; ++r) {
                int rl = wr + 16 * i + 4 * l4 + r;
                float z2v = z2s[rl];
                float s = 0.f;
#pragma unroll
                for (int j = 0; j < 4; ++j) {
                    int cl = wc + 16 * j + l15;
                    float d2 = z2v + c2s[cl] - 2.0f * acc[i][j][r];
                    float d = sqrtf(fmaxf(d2, 1e-12f));
                    s += __expf(SHIFTC - d);
                }
                s += __shfl_xor(s, 1); s += __shfl_xor(s, 2);
                s += __shfl_xor(s, 4); s += __shfl_xor(s, 8);
                if (l15 == 0) atomicAdd(&Sg[r0 + rl], s);
            }
        }
    } else {
#pragma unroll
        for (int j = 0; j < 4; ++j) {
            int cl = wc + 16 * j + l15;
            float c2v = c2s[cl];
            float cs = 0.f;
#pragma unroll
            for (int i = 0; i < 4; ++i) {
#pragma unroll
                for (int r = 0; r < 4; ++r) {
                    int rl = wr + 16 * i + 4 * l4 + r;
                    float d2 = z2s[rl] + c2v - 2.0f * acc[i][j][r];
                    float d = sqrtf(fmaxf(d2, 1e-12f));
                    cs += __expf(SHIFTC - d) * rs[rl];
                }
            }
            cs += __shfl_xor(cs, 16); cs += __shfl_xor(cs, 32);
            if (l4 == 0) atomicAdd(&cd[c0 + cl], cs);
        }
    }
}

// ---------------- finalize: reduce slices, normalize, entropy (1024 thr) --------
__global__ __launch_bounds__(1024) void k_final(const float* __restrict__ cdp,
                                                float* __restrict__ out) {
    __shared__ float red[16];
    __shared__ float tot_s;
    int tid = threadIdx.x, lane = tid & 63, wave = tid >> 6;
    float vloc[4];
    float t = 0.f;
#pragma unroll
    for (int q = 0; q < 4; ++q) {
        int i = tid + q * 1024;
        float v = 0.f;
#pragma unroll
        for (int s = 0; s < NSLICE; ++s) v += cdp[(size_t)s * NCODES + i];
        vloc[q] = v;
        t += v;
    }
#pragma unroll
    for (int off = 32; off >= 1; off >>= 1) t += __shfl_down(t, off);
    if (lane == 0) red[wave] = t;
    __syncthreads();
    if (tid == 0) {
        float tt = 0.f;
#pragma unroll
        for (int w = 0; w < 16; ++w) tt += red[w];
        tot_s = tt;
    }
    __syncthreads();
    float inv = 1.0f / (tot_s + 1e-8f);
    float e = 0.f;
#pragma unroll
    for (int q = 0; q < 4; ++q) {
        float p = vloc[q] * inv;
        e += p * __logf(p + 1e-8f);
    }
#pragma unroll
    for (int off = 32; off >= 1; off >>= 1) e += __shfl_down(e, off);
    if (lane == 0) red[wave] = e;
    __syncthreads();
    if (tid == 0) {
        float ee = 0.f;
#pragma unroll
        for (int w = 0; w < 16; ++w) ee += red[w];
        out[0] = 1.0f - (-ee) / __logf((float)NCODES);
    }
}

// ---------------- launcher ----------------
extern "C" void kernel_launch(void* const* d_in, const int* in_sizes, int n_in,
                              void* d_out, int out_size, void* d_ws, size_t ws_size,
                              hipStream_t stream) {
    const float* sf = (const float*)d_in[0];
    const float* cb = (const float*)d_in[1];
    const int* lengths = (const int*)d_in[2];
    const int* stride_p = (const int*)d_in[3];

    float* Sg = (float*)d_ws;                      // NROWS_PAD
    float* cdp = Sg + NROWS_PAD;                   // NSLICE * NCODES
    float* z2 = cdp + (size_t)NSLICE * NCODES;     // NROWS_PAD (atomic-accumulated)
    float* c2 = z2 + NROWS_PAD;                    // NCODES
    unsigned short* zbf = (unsigned short*)(c2 + NCODES);       // NROWS_PAD*DIM bf16
    unsigned short* cbbf = zbf + (size_t)NROWS_PAD * DIM;       // NCODES*DIM bf16
    unsigned short* Eg = cbbf + (size_t)NCODES * DIM;           // NROWS_PAD*NCODES bf16

    size_t base_bytes = (size_t)(2 * NROWS_PAD + NCODES) * 4
                      + (size_t)NSLICE * NCODES * 4
                      + ((size_t)NROWS_PAD * DIM + (size_t)NCODES * DIM) * 2;
    size_t need = base_bytes + (size_t)NROWS_PAD * NCODES * 2;

    // zero Sg, cdp, z2 (contiguous)
    hipMemsetAsync(Sg, 0, ((size_t)2 * NROWS_PAD + (size_t)NSLICE * NCODES) * sizeof(float), stream);
    k_transpose<<<dim3((TT + 31) / 32, DIM / 32, NUM_B), 256, 0, stream>>>(sf, zbf, z2);
    k_cb<<<dim3(NCODES / 4), 256, 0, stream>>>(cb, cbbf, c2);
    if (ws_size >= need) {
        k_gemm1<<<dim3(NCODES / 128, ROW_TILES), 256, 0, stream>>>(zbf, cbbf, z2, c2, lengths, stride_p, Sg, Eg);
        k_scan<<<dim3(NCODES / 2048, NROWS_PAD / 32), 256, 0, stream>>>(Eg, Sg, lengths, stride_p, cdp);
    } else {
        k_gemm<1><<<dim3(NCODES / 128, ROW_TILES), 256, 0, stream>>>(zbf, cbbf, z2, c2, lengths, stride_p, Sg, cdp);
        k_gemm<2><<<dim3(NCODES / 128, ROW_TILES), 256, 0, stream>>>(zbf, cbbf, z2, c2, lengths, stride_p, Sg, cdp);
    }
    k_final<<<1, 1024, 0, stream>>>(cdp, (float*)d_out);
}